// Round 19
// baseline (564.523 us; speedup 1.0000x reference)
//
#include <hip/hip_runtime.h>
#include <cstddef>

#define TPB 256

typedef unsigned short ushort_t;
typedef __attribute__((ext_vector_type(8))) short s8v;
typedef __attribute__((ext_vector_type(4))) float f4v;
typedef __attribute__((ext_vector_type(4))) unsigned u4v;

#define MFMA16(a, b, c) __builtin_amdgcn_mfma_f32_16x16x32_bf16((a), (b), (c), 0, 0, 0)

static const int NB   = 32;
static const int NPIX = 1024;
static const int CIN  = 264;
static const int C1   = 128;
static const int C2   = 256;
static const int VF_  = 258;
static const int DS_  = 300;
static const int LL   = 20;

__device__ __forceinline__ ushort_t f2b(float x) {
  unsigned u = __builtin_bit_cast(unsigned, x);
  u = (u + 0x7fffu + ((u >> 16) & 1u)) >> 16;
  return (ushort_t)u;
}
__device__ __forceinline__ float b2f(ushort_t h) {
  unsigned u = ((unsigned)h) << 16;
  return __builtin_bit_cast(float, u);
}

// ---------------- fused prep kernel ----------------
__global__ __launch_bounds__(TPB) void k_prep(
    const float* __restrict__ c1w, const float* __restrict__ c2w,
    const float* __restrict__ kw, const float* __restrict__ qw,
    const float* __restrict__ vw,
    const float* __restrict__ txt, const float* __restrict__ iw,
    const float* __restrict__ ib,
    const float* __restrict__ video, const float* __restrict__ spatial,
    ushort_t* __restrict__ w1r, ushort_t* __restrict__ w2r,
    ushort_t* __restrict__ wcat,
    float* __restrict__ mod, ushort_t* __restrict__ x0h) {
  int bid = blockIdx.x;
  const int tid = threadIdx.x;

  if (bid < 1296) {
    int i = bid * TPB + tid;
    if (i < 9 * 9 * 128 * 32) {
      int j = i & 31;
      int oc = (i >> 5) % 128;
      int ts = (i >> 5) / 128;
      int s = ts % 9, t = ts / 9;
      int ic = s * 32 + j;
      float v = (ic < 264) ? c1w[((size_t)oc * 264 + ic) * 9 + t] : 0.f;
      w1r[i] = f2b(v);
    }
    return;
  }
  bid -= 1296;
  if (bid < 1152) {
    int i = bid * TPB + tid;
    if (i < 9 * 4 * 256 * 32) {
      int j = i & 31;
      int oc = (i >> 5) % 256;
      int ts = (i >> 5) / 256;
      int s = ts % 4, t = ts / 4;
      int ic = s * 32 + j;
      float v = (ic < 128) ? c2w[((size_t)oc * 128 + ic) * 9 + t] : 0.f;
      w2r[i] = f2b(v);
    }
    return;
  }
  bid -= 1152;
  if (bid < 3 * 432) {
    int which = bid / 432;
    int i = (bid - which * 432) * TPB + tid;
    if (i < 384 * 288) {
      int n = i / 288, k = i - n * 288;
      const float* src = (which == 0) ? kw : (which == 1) ? qw : vw;
      float v = (n < 258 && k < 258) ? src[(size_t)n * 258 + k] : 0.f;
      wcat[(size_t)which * 110592 + i] = f2b(v);
    }
    return;
  }
  bid -= 3 * 432;
  if (bid < 32) {
    int b = bid;
    __shared__ float tm[DS_];
    for (int d = tid; d < DS_; d += TPB) {
      const float* p = txt + ((size_t)b * DS_ + d) * LL;
      float m = p[0];
      for (int l = 1; l < LL; ++l) m = fmaxf(m, p[l]);
      tm[d] = m;
    }
    __syncthreads();
    for (int oc = tid; oc < VF_; oc += TPB) {
      const float* wr = iw + (size_t)oc * DS_;
      float s = ib[oc];
      for (int d = 0; d < DS_; ++d) s += tm[d] * wr[d];
      mod[(size_t)b * VF_ + oc] = s;
    }
    return;
  }
  bid -= 32;
  {
    const int pb = bid & 15;
    const int b = bid >> 4;
    __shared__ ushort_t lds[264][72];
    for (int u = tid; u < 264 * 64; u += TPB) {
      int c = u >> 6, px = u & 63;
      int p = (pb << 6) + px;
      float v = (c < 256) ? video[(((size_t)b * 256 + c) << 10) + p]
                          : spatial[(((size_t)b * 8 + (c - 256)) << 10) + p];
      lds[c][px] = f2b(v);
    }
    __syncthreads();
    for (int u = tid; u < 64 * 36; u += TPB) {
      int px = u / 36, ch = u - px * 36;
      s8v v;
#pragma unroll
      for (int j = 0; j < 8; ++j) {
        int ic = ch * 8 + j;
        v[j] = (ic < 264) ? (short)lds[ic][px] : (short)0;
      }
      *(s8v*)(x0h + ((size_t)((b << 10) + (pb << 6) + px)) * 288 + ch * 8) = v;
    }
  }
}

// ---------------- W_l = rw^T @ txt + bias_l = rb @ txt ----------------
__global__ __launch_bounds__(384) void k_wl(const float* __restrict__ rw,
                                            const float* __restrict__ rb,
                                            const float* __restrict__ txt,
                                            float* __restrict__ wl,
                                            float* __restrict__ bias_l) {
  const int b = blockIdx.x;
  const int tid = threadIdx.x;
  __shared__ float tl[DS_ * LL];
  for (int i = tid; i < DS_ * LL; i += 384) tl[i] = txt[(size_t)b * DS_ * LL + i];
  __syncthreads();
  if (tid < 288) {
    int k = tid;
    float acc[LL];
#pragma unroll
    for (int l = 0; l < LL; ++l) acc[l] = 0.f;
    if (k < VF_) {
      for (int n = 0; n < DS_; ++n) {
        float w = rw[(size_t)n * VF_ + k];
        const float* tr = tl + n * LL;
#pragma unroll
        for (int l = 0; l < LL; ++l) acc[l] += w * tr[l];
      }
    }
#pragma unroll
    for (int l = 0; l < LL; ++l) wl[((size_t)b * 288 + k) * LL + l] = acc[l];
  }
  if (tid >= 288 && tid < 288 + LL) {
    int l = tid - 288;
    float s = 0.f;
    for (int n = 0; n < DS_; ++n) s += rb[n] * tl[n * LL + l];
    bias_l[(size_t)b * LL + l] = s;
  }
}

// ---------------- GN finalize (stats1 -> scale/shift) ----------------
__global__ __launch_bounds__(64) void k_gnfin(const float* __restrict__ stats,
                                              const float* __restrict__ gamma,
                                              const float* __restrict__ beta,
                                              float* __restrict__ scale,
                                              float* __restrict__ shift,
                                              int C, int cpg) {
  const int g = blockIdx.x, b = blockIdx.y;
  const int n = cpg << 4;
  float s = 0.f, q = 0.f;
  for (int i = threadIdx.x; i < n; i += 64) {
    int c = g * cpg + (i >> 4), pxb = i & 15;
    size_t idx = ((((size_t)b * C + c) << 4) + pxb) << 1;
    s += stats[idx];
    q += stats[idx + 1];
  }
#pragma unroll
  for (int off = 32; off > 0; off >>= 1) {
    s += __shfl_xor(s, off);
    q += __shfl_xor(q, off);
  }
  const float M = (float)(cpg << 10);
  float mean = s / M;
  float rsig = rsqrtf(q / M - mean * mean + 1e-5f);
  if ((int)threadIdx.x < cpg) {
    int c = g * cpg + threadIdx.x;
    float sc = rsig * gamma[c];
    scale[(size_t)b * C + c] = sc;
    shift[(size_t)b * C + c] = beta[c] - mean * sc;
  }
}

// ---------------- conv 3x3 via bf16 MFMA implicit GEMM (+GN stats, bf16 NHWC out) ----------------
template <int ICG, int GN>
__global__ __launch_bounds__(TPB) void k_conv_mfma(const ushort_t* __restrict__ in_h,
                                                   const ushort_t* __restrict__ wr,
                                                   const float* __restrict__ bias,
                                                   const float* __restrict__ iscale,
                                                   const float* __restrict__ ishift,
                                                   ushort_t* __restrict__ outp,
                                                   float* __restrict__ stats, int Cout) {
  const int ICPAD = ICG * 8;
  const int NS = ICG / 4;
  const int ICGS = 4 * 34 * 8 + 24;
  const int b   = blockIdx.z;
  const int ocb = blockIdx.y << 7;
  const int pxb = blockIdx.x;
  const int tid = threadIdx.x;
  const int w = tid >> 6, lane = tid & 63;
  const int lhi = lane >> 4, llo = lane & 15;

  __shared__ ushort_t in_t[ICG * ICGS];
  __shared__ float sc_l[GN ? ICG * 8 : 1], sh_l[GN ? ICG * 8 : 1];

  if (GN) {
    for (int i = tid; i < ICPAD; i += TPB) {
      sc_l[i] = iscale[(size_t)b * ICPAD + i];
      sh_l[i] = ishift[(size_t)b * ICPAD + i];
    }
    __syncthreads();
  }

  for (int u = tid; u < ICG * 8; u += TPB) {
    int icg = u >> 3, rem = u & 7, row = rem >> 1, col = (rem & 1) ? 33 : 0;
    *(s8v*)&in_t[icg * ICGS + (row * 34 + col) * 8] = (s8v){0, 0, 0, 0, 0, 0, 0, 0};
  }
  for (int r = 0; r < 4; ++r) {
    int gy = (pxb << 1) - 1 + r;
    if ((unsigned)gy < 32u) {
      const ushort_t* src = in_h + ((size_t)((b << 10) + (gy << 5))) * ICPAD;
      for (int u = tid; u < 32 * ICG; u += TPB) {
        int px = u / ICG, icg = u - px * ICG;
        s8v raw = *(const s8v*)(src + u * 8);
        if (GN) {
          s8v vv;
#pragma unroll
          for (int j = 0; j < 8; ++j) {
            int c = icg * 8 + j;
            float f = fmaxf(b2f((ushort_t)raw[j]) * sc_l[c] + sh_l[c], 0.f);
            vv[j] = (short)f2b(f);
          }
          raw = vv;
        }
        *(s8v*)&in_t[icg * ICGS + (r * 34 + px + 1) * 8] = raw;
      }
    } else {
      for (int u = tid; u < 32 * ICG; u += TPB) {
        int px = u / ICG, icg = u - px * ICG;
        *(s8v*)&in_t[icg * ICGS + (r * 34 + px + 1) * 8] = (s8v){0, 0, 0, 0, 0, 0, 0, 0};
      }
    }
  }
  __syncthreads();

  f4v acc[2][4];
#pragma unroll
  for (int i = 0; i < 2; ++i)
#pragma unroll
    for (int m = 0; m < 4; ++m) acc[i][m] = (f4v){0.f, 0.f, 0.f, 0.f};

  for (int t = 0; t < 9; ++t) {
    const int ky = t / 3, kx = t - ky * 3;
#pragma unroll
    for (int s = 0; s < NS; ++s) {
      const ushort_t* wp = wr + (((size_t)(t * NS + s) * Cout + ocb + w * 32 + llo) << 5) + lhi * 8;
      s8v a0 = *(const s8v*)(wp);
      s8v a1 = *(const s8v*)(wp + (16 << 5));
      const int icg = (s << 2) + lhi;
#pragma unroll
      for (int m = 0; m < 4; ++m) {
        const int row = (m >> 1) + ky;
        const int col = ((m & 1) << 4) + llo + kx;
        s8v bm = *(const s8v*)&in_t[icg * ICGS + (row * 34 + col) * 8];
        acc[0][m] = MFMA16(a0, bm, acc[0][m]);
        acc[1][m] = MFMA16(a1, bm, acc[1][m]);
      }
    }
  }

  __syncthreads();
  ushort_t* tb = in_t;  // [64 px][136]

#pragma unroll
  for (int i = 0; i < 2; ++i) {
#pragma unroll
    for (int r = 0; r < 4; ++r) {
      const int oc = ocb + w * 32 + i * 16 + lhi * 4 + r;
      const float bv = bias[oc];
      float sm = 0.f, sq = 0.f;
#pragma unroll
      for (int m = 0; m < 4; ++m) {
        float v = acc[i][m][r] + bv;
        tb[((m << 4) + llo) * 136 + (w * 32 + i * 16 + lhi * 4 + r)] = f2b(v);
        sm += v;
        sq += v * v;
      }
#pragma unroll
      for (int off = 1; off < 16; off <<= 1) {
        sm += __shfl_xor(sm, off);
        sq += __shfl_xor(sq, off);
      }
      if (llo == 0) {
        size_t sidx = ((((size_t)b * Cout + oc) << 4) + pxb) << 1;
        stats[sidx] = sm;
        stats[sidx + 1] = sq;
      }
    }
  }

  __syncthreads();
  for (int u = tid; u < 64 * 16; u += TPB) {
    int px = u >> 4, ch = u & 15;
    s8v val = *(const s8v*)&tb[px * 136 + ch * 8];
    *(s8v*)&outp[((size_t)((b << 10) + (pxb << 6) + px)) * Cout + ocb + ch * 8] = val;
  }
}

// x2raw NHWC bf16 + GN(folded gnfin)+relu + coords -> vso_h bf16 [b][1024][288]
__global__ __launch_bounds__(TPB) void k_build_vsoh(const ushort_t* __restrict__ x2raw,
                                                    const float* __restrict__ stats,
                                                    const float* __restrict__ gamma,
                                                    const float* __restrict__ beta,
                                                    ushort_t* __restrict__ dst) {
  const int pb = blockIdx.x;
  const int b  = blockIdx.y;
  const int tid = threadIdx.x;
  __shared__ float st_l[8192];
  __shared__ float sc_l[256], sh_l[256];
  for (int i = tid; i < 8192; i += TPB) st_l[i] = stats[(size_t)b * 8192 + i];
  __syncthreads();
  {
    int c = tid, g = c >> 3;
    float s = 0.f, q = 0.f;
    for (int j = 0; j < 8; ++j)
      for (int p = 0; p < 16; ++p) {
        int idx = (((g << 3) + j) * 16 + p) * 2;
        s += st_l[idx];
        q += st_l[idx + 1];
      }
    float mean = s / 8192.f;
    float rsig = rsqrtf(q / 8192.f - mean * mean + 1e-5f);
    float sc = rsig * gamma[c];
    sc_l[c] = sc;
    sh_l[c] = beta[c] - mean * sc;
  }
  __syncthreads();
  for (int u = tid; u < 64 * 36; u += TPB) {
    int px = u / 36, ch = u - px * 36;
    int p = (pb << 6) + px;
    s8v v;
    if (ch < 32) {
      s8v raw = *(const s8v*)(x2raw + ((size_t)((b << 10) + p)) * 256 + ch * 8);
#pragma unroll
      for (int j = 0; j < 8; ++j) {
        int c = ch * 8 + j;
        float f = fmaxf(b2f((ushort_t)raw[j]) * sc_l[c] + sh_l[c], 0.f);
        v[j] = (short)f2b(f);
      }
    } else {
#pragma unroll
      for (int j = 0; j < 8; ++j) {
        int cg = ch * 8 + j;
        float fv;
        if (cg == 256)      fv = -1.f + (2.f / 31.f) * (float)(p & 31);
        else if (cg == 257) fv = -1.f + (2.f / 31.f) * (float)(p >> 5);
        else                fv = 0.f;
        v[j] = (short)f2b(fv);
      }
    }
    *(s8v*)(dst + ((size_t)((b << 10) + p)) * 288 + ch * 8) = v;
  }
}

// ---------------- bf16 MFMA GEMM (LDS-bounced coalesced epilogues) ----------------
template <int MODE>
__global__ __launch_bounds__(TPB) void k_gemm_mfma(const ushort_t* __restrict__ A,
                                                   const ushort_t* __restrict__ Bw,
                                                   void* __restrict__ Cout,
                                                   const float* __restrict__ bias,
                                                   const float* __restrict__ mod) {
  const int wg = blockIdx.x;
  const int xcd = wg & 7;
  const int s2 = wg >> 3;
  const int b = xcd * 4 + (s2 / 24);
  const int rem = s2 - (s2 / 24) * 24;
  const int n0 = (rem % 3) << 7;
  const int m0 = (rem / 3) << 7;
  const int tid = threadIdx.x;
  const int w = tid >> 6, lane = tid & 63;
  const int wr = w >> 1, wc = w & 1;
  const int lhi = lane >> 4, llo = lane & 15;

  __shared__ ushort_t smem[2 * 128 * 40];
  ushort_t* A_l = smem;
  ushort_t* B_l = smem + 128 * 40;

  f4v acc[4][4];
#pragma unroll
  for (int i = 0; i < 4; ++i)
#pragma unroll
    for (int j = 0; j < 4; ++j) acc[i][j] = (f4v){0.f, 0.f, 0.f, 0.f};

  const ushort_t* Ab = A + (((size_t)b << 10)) * 288;

  for (int k0 = 0; k0 < 288; k0 += 32) {
    for (int u = tid; u < 512; u += TPB) {
      int row = u >> 2, seg = u & 3;
      *(s8v*)&A_l[row * 40 + seg * 8] = *(const s8v*)(Ab + (size_t)(m0 + row) * 288 + k0 + seg * 8);
      *(s8v*)&B_l[row * 40 + seg * 8] = *(const s8v*)(Bw + (size_t)(n0 + row) * 288 + k0 + seg * 8);
    }
    __syncthreads();
    s8v am[4], bn[4];
#pragma unroll
    for (int i = 0; i < 4; ++i) am[i] = *(const s8v*)&A_l[(wr * 64 + i * 16 + llo) * 40 + lhi * 8];
#pragma unroll
    for (int j = 0; j < 4; ++j) bn[j] = *(const s8v*)&B_l[(wc * 64 + j * 16 + llo) * 40 + lhi * 8];
#pragma unroll
    for (int i = 0; i < 4; ++i)
#pragma unroll
      for (int j = 0; j < 4; ++j) {
        if (MODE == 2) acc[i][j] = MFMA16(bn[j], am[i], acc[i][j]);
        else           acc[i][j] = MFMA16(am[i], bn[j], acc[i][j]);
      }
    __syncthreads();
  }

  ushort_t* T = smem;  // [64][136]

  if (MODE == 1) {
    ushort_t* Cb = (ushort_t*)Cout + (size_t)b * 1024 * 288;
    const int nch = (n0 == 256) ? 4 : 16;
#pragma unroll
    for (int h = 0; h < 2; ++h) {
      __syncthreads();
      if (wr == h) {
#pragma unroll
        for (int j = 0; j < 4; ++j) {
          int n = n0 + wc * 64 + j * 16 + llo;
          bool real = n < VF_;
          float bv = real ? bias[n] : 0.f;
          float sm = real ? mod[(size_t)b * VF_ + n] : 0.f;
          int coll = wc * 64 + j * 16 + llo;
#pragma unroll
          for (int i = 0; i < 4; ++i)
#pragma unroll
            for (int r = 0; r < 4; ++r) {
              int rowl = i * 16 + lhi * 4 + r;
              T[rowl * 136 + coll] = f2b(real ? (acc[i][j][r] + bv) * sm : 0.f);
            }
        }
      }
      __syncthreads();
      for (int u = tid; u < 64 * nch; u += TPB) {
        int rowl = u / nch, ch = u - rowl * nch;
        int m = m0 + h * 64 + rowl;
        *(s8v*)&Cb[(size_t)m * 288 + n0 + ch * 8] = *(const s8v*)&T[rowl * 136 + ch * 8];
      }
    }
  } else {
    ushort_t* Cb = (ushort_t*)Cout + (size_t)b * 32 * 272 * 32;
    const int mc0 = m0 >> 5;
#pragma unroll
    for (int h = 0; h < 2; ++h) {
      __syncthreads();
      if (wc == h) {
#pragma unroll
        for (int j = 0; j < 4; ++j)
#pragma unroll
          for (int r = 0; r < 4; ++r) {
            int n = n0 + h * 64 + j * 16 + lhi * 4 + r;
            int rowl = j * 16 + lhi * 4 + r;
            bool real = n < VF_;
            float bv = real ? bias[n] : 0.f;
#pragma unroll
            for (int i = 0; i < 4; ++i) {
              int coll = wr * 64 + i * 16 + llo;
              T[rowl * 136 + coll] = f2b(real ? acc[i][j][r] + bv : 0.f);
            }
          }
      }
      __syncthreads();
      for (int u = tid; u < 64 * 16; u += TPB) {
        int rowl = u >> 4, ch = u & 15;
        int n = n0 + h * 64 + rowl;
        if (n >= 272) continue;
        int mcblk = ch >> 2, within = ch & 3;
        *(s8v*)&Cb[(((size_t)(mc0 + mcblk) * 272 + n) << 5) + within * 8] =
            *(const s8v*)&T[rowl * 136 + ch * 8];
      }
    }
  }
}

// ---------------- txt cross-attention v3 (LDS-staged vsoh reads) ----------------
__global__ __launch_bounds__(TPB) void k_txtattn(const ushort_t* __restrict__ vsoh,
                                                 const float* __restrict__ wl,
                                                 const float* __restrict__ bias_l,
                                                 const float* __restrict__ txt,
                                                 float* __restrict__ out) {
  const int b = blockIdx.y;
  const int p0 = blockIdx.x << 8;
  const int tid = threadIdx.x;
  __shared__ float wls[288 * LL];
  __shared__ float tl[DS_ * LL];
  __shared__ float vs_l[256][33];
  for (int i = tid; i < 288 * LL; i += TPB) wls[i] = wl[(size_t)b * 288 * LL + i];
  for (int i = tid; i < DS_ * LL; i += TPB) tl[i] = txt[(size_t)b * DS_ * LL + i];

  float lg[LL];
  {
    const float* bl = bias_l + (size_t)b * LL;
#pragma unroll
    for (int l = 0; l < LL; ++l) lg[l] = bl[l];
  }

  for (int cc = 0; cc < 9; ++cc) {
    __syncthreads();
    for (int u = tid; u < 1024; u += TPB) {
      int px = u >> 2, seg = u & 3;
      s8v raw = *(const s8v*)(vsoh + ((size_t)((b << 10) + p0 + px)) * 288 + cc * 32 + seg * 8);
#pragma unroll
      for (int j = 0; j < 8; ++j) vs_l[px][seg * 8 + j] = b2f((ushort_t)raw[j]);
    }
    __syncthreads();
    const float* vrow = vs_l[tid];
#pragma unroll 4
    for (int j = 0; j < 32; ++j) {
      float f = vrow[j];
      const float* wr = &wls[(cc * 32 + j) * LL];
#pragma unroll
      for (int l = 0; l < LL; ++l) lg[l] += f * wr[l];
    }
  }

  const float sc = 0.057735026919f;  // 1/sqrt(300)
  float mx = lg[0] * sc;
#pragma unroll
  for (int l = 1; l < LL; ++l) mx = fmaxf(mx, lg[l] * sc);
  float sum = 0.f;
#pragma unroll
  for (int l = 0; l < LL; ++l) {
    lg[l] = __expf(lg[l] * sc - mx);
    sum += lg[l];
  }
  float inv = 1.f / sum;
#pragma unroll
  for (int l = 0; l < LL; ++l) lg[l] *= inv;
  float* ob = out + (((size_t)b * 558 + VF_) << 10) + p0 + tid;
  for (int d = 0; d < DS_; ++d) {
    const float* tr = tl + d * LL;
    float s = 0.f;
#pragma unroll
    for (int l = 0; l < LL; ++l) s += lg[l] * tr[l];
    ob[(size_t)d << 10] = s;
  }
}

// ---------------- video self-attention: bf16 MFMA flash v8 ----------------
// Stride-34 fragment rows: LDS bank spread (17-dword stride, max 4-way vs 8-way).
__global__ __launch_bounds__(256, 2) void k_flash_mfma(const ushort_t* __restrict__ Kb,
                                                       const ushort_t* __restrict__ Qb,
                                                       const ushort_t* __restrict__ Vtb,
                                                       float* __restrict__ out) {
  const int wg = blockIdx.x;
  const int xcd = wg & 7, s = wg >> 3;
  const int b = xcd * 4 + (s >> 4);
  const int n0 = (s & 15) << 6;
  const int tid = threadIdx.x;
  const int w = tid >> 6, lane = tid & 63;
  const int lhi = lane >> 4;
  const int llo = lane & 15;

  // q: per ks, 2 halves x 16 rows x 34 elems = 1088; v: per dt, 16 rows x 34 = 544
  __shared__ ushort_t q_l[2][9 * 1088];
  __shared__ ushort_t v_l[2][17 * 544];

  s8v kf[9];
  {
    const ushort_t* kp = Kb + ((size_t)(b * 1024 + n0 + w * 16 + llo)) * 288 + lhi * 8;
#pragma unroll
    for (int ks = 0; ks < 9; ++ks) kf[ks] = *(const s8v*)(kp + ks * 32);
  }

  const ushort_t* Qbase = Qb + (((size_t)b << 10)) * 288;
  const ushort_t* Vbase = Vtb + (size_t)b * 32 * 272 * 32;

  s8v qs[5], vs[5];
  auto ISSUE = [&](int mc) {
#pragma unroll
    for (int i = 0; i < 5; ++i) {
      int u = tid + (i << 8);
      if (u < 1152) {
        int ks = u >> 7, t = u & 127;
        int row = t >> 2;
        int seg = t & 3;
        qs[i] = *(const s8v*)(Qbase + (size_t)((mc << 5) + row) * 288 + ks * 32 + seg * 8);
      }
      if (u < 1088) vs[i] = *(const s8v*)(Vbase + (size_t)mc * 8704 + (u << 3));
    }
  };
  auto WRITE = [&](int buf) {
#pragma unroll
    for (int i = 0; i < 5; ++i) {
      int u = tid + (i << 8);
      if (u < 1152) {
        int ks = u >> 7, t = u & 127;
        int r = t >> 2, seg = t & 3;
        *(s8v*)&q_l[buf][ks * 1088 + (r >> 4) * 544 + (r & 15) * 34 + (seg << 3)] = qs[i];
      }
      if (u < 1088) {
        int dt = u >> 6, t = u & 63;
        *(s8v*)&v_l[buf][dt * 544 + (t >> 2) * 34 + ((t & 3) << 3)] = vs[i];
      }
    }
  };

  f4v oacc[17];
#pragma unroll
  for (int i = 0; i < 17; ++i) oacc[i] = (f4v){0.f, 0.f, 0.f, 0.f};
  float mreg = -1e30f, lreg = 0.f;

  const float sc = 0.0622572819f;  // 1/sqrt(258)
  const int srcA = llo + ((lhi & 1) << 5);
  const int srcB = srcA + 16;
  const bool hi2 = lhi >= 2;
  const int qoff = llo * 34 + (lhi << 3);

  ISSUE(0);
  WRITE(0);
  __syncthreads();
  ISSUE(1);

  for (int mc = 0; mc < 32; ++mc) {
    const int cur = mc & 1;
    const ushort_t* ql = q_l[cur];
    const ushort_t* vl = v_l[cur];

    f4v sacc0 = {0.f, 0.f, 0.f, 0.f}, sacc1 = {0.f, 0.f, 0.f, 0.f};
    __builtin_amdgcn_s_setprio(1);
#pragma unroll
    for (int ks = 0; ks < 9; ++ks) {
      s8v q0 = *(const s8v*)&ql[ks * 1088 + qoff];
      s8v q1 = *(const s8v*)&ql[ks * 1088 + 544 + qoff];
      sacc0 = MFMA16(q0, kf[ks], sacc0);
      sacc1 = MFMA16(q1, kf[ks], sacc1);
    }
    __builtin_amdgcn_s_setprio(0);

    float pmax = fmaxf(fmaxf(fmaxf(sacc0[0], sacc0[1]), fmaxf(sacc0[2], sacc0[3])),
                       fmaxf(fmaxf(sacc1[0], sacc1[1]), fmaxf(sacc1[2], sacc1[3])));
    pmax = fmaxf(pmax, __shfl_xor(pmax, 16));
    pmax = fmaxf(pmax, __shfl_xor(pmax, 32));
    float mn = fmaxf(mreg, pmax * sc);
    float alpha = __expf(mreg - mn);
    mreg = mn;

    float p0[4], p1[4];
    float rsum = 0.f;
#pragma unroll
    for (int r = 0; r < 4; ++r) {
      p0[r] = __expf(sacc0[r] * sc - mn);
      p1[r] = __expf(sacc1[r] * sc - mn);
      rsum += p0[r] + p1[r];
    }
    rsum += __shfl_xor(rsum, 16);
    rsum += __shfl_xor(rsum, 32);
    lreg = lreg * alpha + rsum;

    unsigned u0, u1, u2, u3;
    asm("v_cvt_pk_bf16_f32 %0, %1, %2" : "=v"(u0) : "v"(p0[0]), "v"(p0[1]));
    asm("v_cvt_pk_bf16_f32 %0, %1, %2" : "=v"(u1) : "v"(p0[2]), "v"(p0[3]));
    asm("v_cvt_pk_bf16_f32 %0, %1, %2" : "=v"(u2) : "v"(p1[0]), "v"(p1[1]));
    asm("v_cvt_pk_bf16_f32 %0, %1, %2" : "=v"(u3) : "v"(p1[2]), "v"(p1[3]));
    unsigned s0a = __shfl(u0, srcA, 64), s2a = __shfl(u2, srcA, 64);
    unsigned s1a = __shfl(u1, srcA, 64), s3a = __shfl(u3, srcA, 64);
    unsigned s0b = __shfl(u0, srcB, 64), s2b = __shfl(u2, srcB, 64);
    unsigned s1b = __shfl(u1, srcB, 64), s3b = __shfl(u3, srcB, 64);
    u4v pu;
    pu[0] = hi2 ? s2a : s0a;
    pu[1] = hi2 ? s3a : s1a;
    pu[2] = hi2 ? s2b : s0b;
    pu[3] = hi2 ? s3b : s1b;
    s8v pf = __builtin_bit_cast(s8v, pu);

    __builtin_amdgcn_s_setprio(1);
#pragma unroll
    for (int dt = 0; dt < 17; ++dt) {
      s8v vf = *(const s8v*)&vl[dt * 544 + qoff];
      f4v o = oacc[dt];
      o[0] *= alpha; o[1] *= alpha; o[2] *= alpha; o[3] *= alpha;
      oacc[dt] = MFMA16(vf, pf, o);
    }
    __builtin_amdgcn_s_setprio(0);

    if (mc < 31) {
      WRITE(cur ^ 1);
      if (mc < 30) ISSUE(mc + 2);
    }
    __syncthreads();
  }

  float linv = 1.f / lreg;
  const int n = n0 + w * 16 + llo;
#pragma unroll
  for (int dt = 0; dt < 17; ++dt) {
#pragma unroll
    for (int r = 0; r < 4; ++r) {
      int d = dt * 16 + lhi * 4 + r;
      if (d < VF_) out[((size_t)(b * 558 + d) << 10) + n] = oacc[dt][r] * linv;
    }
  }
}

// ---------------- launcher ----------------
extern "C" void kernel_launch(void* const* d_in, const int* in_sizes, int n_in,
                              void* d_out, int out_size, void* d_ws, size_t ws_size,
                              hipStream_t stream) {
  const float* spatial = (const float*)d_in[0];
  const float* video   = (const float*)d_in[1];
  const float* txt     = (const float*)d_in[2];
  const float* c1w = (const float*)d_in[3];
  const float* c1b = (const float*)d_in[4];
  const float* g1g = (const float*)d_in[5];
  const float* g1b = (const float*)d_in[6];
  const float* c2w = (const float*)d_in[7];
  const float* c2b = (const float*)d_in[8];
  const float* g2g = (const float*)d_in[9];
  const float* g2b = (const float*)d_in[10];
  const float* rw  = (const float*)d_in[11];
  const float* rb  = (const float*)d_in[12];
  const float* kw  = (const float*)d_in[13];
  const float* kb  = (const float*)d_in[14];
  const float* qw  = (const float*)d_in[15];
  const float* qb  = (const float*)d_in[16];
  const float* vw  = (const float*)d_in[17];
  const float* vb  = (const float*)d_in[18];
  const float* iw  = (const float*)d_in[19];
  const float* ib  = (const float*)d_in[20];
  float* out = (float*)d_out;
  float* ws = (float*)d_ws;

  // ws layout (float offsets), lifetime-aliased
  ushort_t* x0h    = (ushort_t*)(ws + 0);          // dead after conv1
  ushort_t* x1raw  = (ushort_t*)(ws + 5000000);    // dead after conv2
  ushort_t* kb16   = (ushort_t*)(ws + 10000000);
  ushort_t* x2raw  = (ushort_t*)(ws + 11500000);   // dead before kq GEMMs
  ushort_t* qb16   = (ushort_t*)(ws + 15800000);
  ushort_t* vsoh   = (ushort_t*)(ws + 20600000);
  ushort_t* vtb16  = (ushort_t*)(ws + 25400000);
  ushort_t* wcat   = (ushort_t*)(ws + 29900000);
  ushort_t* w1r    = (ushort_t*)(ws + 30140000);
  ushort_t* w2r    = (ushort_t*)(ws + 30310000);
  float*    mod    = ws + 30460000;
  float*    stats1 = ws + 30500000;
  float*    stats2 = ws + 30700000;
  float*    scale1 = ws + 31000000;
  float*    shift1 = ws + 31010000;
  float*    wl     = ws + 31050000;
  float*    bias_l = ws + 31240000;

  k_wl<<<dim3(32), 384, 0, stream>>>(rw, rb, txt, wl, bias_l);

  k_prep<<<dim3(4288), TPB, 0, stream>>>(c1w, c2w, kw, qw, vw, txt, iw, ib,
                                         video, spatial,
                                         w1r, w2r, wcat, mod, x0h);

  k_conv_mfma<36, 0><<<dim3(16, 1, NB), TPB, 0, stream>>>(x0h, w1r, c1b, nullptr, nullptr,
                                                          x1raw, stats1, C1);
  k_gnfin<<<dim3(32, NB), 64, 0, stream>>>(stats1, g1g, g1b, scale1, shift1, C1, 4);

  k_conv_mfma<16, 1><<<dim3(16, 2, NB), TPB, 0, stream>>>(x1raw, w2r, c2b, scale1, shift1,
                                                          x2raw, stats2, C2);
  k_build_vsoh<<<dim3(16, NB), TPB, 0, stream>>>(x2raw, stats2, g2g, g2b, vsoh);

  k_txtattn<<<dim3(4, NB), TPB, 0, stream>>>(vsoh, wl, bias_l, txt, out);

  k_gemm_mfma<1><<<dim3(768), TPB, 0, stream>>>(vsoh, wcat + 0 * 110592, (void*)kb16, kb, mod);
  k_gemm_mfma<1><<<dim3(768), TPB, 0, stream>>>(vsoh, wcat + 1 * 110592, (void*)qb16, qb, mod);
  k_gemm_mfma<2><<<dim3(768), TPB, 0, stream>>>(vsoh, wcat + 2 * 110592, (void*)vtb16, vb, nullptr);

  k_flash_mfma<<<dim3(512), 256, 0, stream>>>(kb16, qb16, vtb16, out);
}

// Round 20
// 354.633 us; speedup vs baseline: 1.5919x; 1.5919x over previous
//
#include <hip/hip_runtime.h>
#include <cstddef>

#define TPB 256

typedef unsigned short ushort_t;
typedef __attribute__((ext_vector_type(8))) short s8v;
typedef __attribute__((ext_vector_type(4))) float f4v;
typedef __attribute__((ext_vector_type(4))) unsigned u4v;

#define MFMA16(a, b, c) __builtin_amdgcn_mfma_f32_16x16x32_bf16((a), (b), (c), 0, 0, 0)

static const int NB   = 32;
static const int NPIX = 1024;
static const int CIN  = 264;
static const int C1   = 128;
static const int C2   = 256;
static const int VF_  = 258;
static const int DS_  = 300;
static const int LL   = 20;

__device__ __forceinline__ ushort_t f2b(float x) {
  unsigned u = __builtin_bit_cast(unsigned, x);
  u = (u + 0x7fffu + ((u >> 16) & 1u)) >> 16;
  return (ushort_t)u;
}
__device__ __forceinline__ float b2f(ushort_t h) {
  unsigned u = ((unsigned)h) << 16;
  return __builtin_bit_cast(float, u);
}

// ---------------- fused prep kernel ----------------
__global__ __launch_bounds__(TPB) void k_prep(
    const float* __restrict__ c1w, const float* __restrict__ c2w,
    const float* __restrict__ kw, const float* __restrict__ qw,
    const float* __restrict__ vw,
    const float* __restrict__ txt, const float* __restrict__ iw,
    const float* __restrict__ ib,
    const float* __restrict__ video, const float* __restrict__ spatial,
    ushort_t* __restrict__ w1r, ushort_t* __restrict__ w2r,
    ushort_t* __restrict__ wcat,
    float* __restrict__ mod, ushort_t* __restrict__ x0h) {
  int bid = blockIdx.x;
  const int tid = threadIdx.x;

  if (bid < 1296) {
    int i = bid * TPB + tid;
    if (i < 9 * 9 * 128 * 32) {
      int j = i & 31;
      int oc = (i >> 5) % 128;
      int ts = (i >> 5) / 128;
      int s = ts % 9, t = ts / 9;
      int ic = s * 32 + j;
      float v = (ic < 264) ? c1w[((size_t)oc * 264 + ic) * 9 + t] : 0.f;
      w1r[i] = f2b(v);
    }
    return;
  }
  bid -= 1296;
  if (bid < 1152) {
    int i = bid * TPB + tid;
    if (i < 9 * 4 * 256 * 32) {
      int j = i & 31;
      int oc = (i >> 5) % 256;
      int ts = (i >> 5) / 256;
      int s = ts % 4, t = ts / 4;
      int ic = s * 32 + j;
      float v = (ic < 128) ? c2w[((size_t)oc * 128 + ic) * 9 + t] : 0.f;
      w2r[i] = f2b(v);
    }
    return;
  }
  bid -= 1152;
  if (bid < 3 * 432) {
    int which = bid / 432;
    int i = (bid - which * 432) * TPB + tid;
    if (i < 384 * 288) {
      int n = i / 288, k = i - n * 288;
      const float* src = (which == 0) ? kw : (which == 1) ? qw : vw;
      float v = (n < 258 && k < 258) ? src[(size_t)n * 258 + k] : 0.f;
      wcat[(size_t)which * 110592 + i] = f2b(v);
    }
    return;
  }
  bid -= 3 * 432;
  if (bid < 32) {
    int b = bid;
    __shared__ float tm[DS_];
    for (int d = tid; d < DS_; d += TPB) {
      const float* p = txt + ((size_t)b * DS_ + d) * LL;
      float m = p[0];
      for (int l = 1; l < LL; ++l) m = fmaxf(m, p[l]);
      tm[d] = m;
    }
    __syncthreads();
    for (int oc = tid; oc < VF_; oc += TPB) {
      const float* wr = iw + (size_t)oc * DS_;
      float s = ib[oc];
      for (int d = 0; d < DS_; ++d) s += tm[d] * wr[d];
      mod[(size_t)b * VF_ + oc] = s;
    }
    return;
  }
  bid -= 32;
  {
    const int pb = bid & 15;
    const int b = bid >> 4;
    __shared__ ushort_t lds[264][72];
    for (int u = tid; u < 264 * 64; u += TPB) {
      int c = u >> 6, px = u & 63;
      int p = (pb << 6) + px;
      float v = (c < 256) ? video[(((size_t)b * 256 + c) << 10) + p]
                          : spatial[(((size_t)b * 8 + (c - 256)) << 10) + p];
      lds[c][px] = f2b(v);
    }
    __syncthreads();
    for (int u = tid; u < 64 * 36; u += TPB) {
      int px = u / 36, ch = u - px * 36;
      s8v v;
#pragma unroll
      for (int j = 0; j < 8; ++j) {
        int ic = ch * 8 + j;
        v[j] = (ic < 264) ? (short)lds[ic][px] : (short)0;
      }
      *(s8v*)(x0h + ((size_t)((b << 10) + (pb << 6) + px)) * 288 + ch * 8) = v;
    }
  }
}

// ---------------- W_l = rw^T @ txt + bias_l = rb @ txt ----------------
__global__ __launch_bounds__(384) void k_wl(const float* __restrict__ rw,
                                            const float* __restrict__ rb,
                                            const float* __restrict__ txt,
                                            float* __restrict__ wl,
                                            float* __restrict__ bias_l) {
  const int b = blockIdx.x;
  const int tid = threadIdx.x;
  __shared__ float tl[DS_ * LL];
  for (int i = tid; i < DS_ * LL; i += 384) tl[i] = txt[(size_t)b * DS_ * LL + i];
  __syncthreads();
  if (tid < 288) {
    int k = tid;
    float acc[LL];
#pragma unroll
    for (int l = 0; l < LL; ++l) acc[l] = 0.f;
    if (k < VF_) {
      for (int n = 0; n < DS_; ++n) {
        float w = rw[(size_t)n * VF_ + k];
        const float* tr = tl + n * LL;
#pragma unroll
        for (int l = 0; l < LL; ++l) acc[l] += w * tr[l];
      }
    }
#pragma unroll
    for (int l = 0; l < LL; ++l) wl[((size_t)b * 288 + k) * LL + l] = acc[l];
  }
  if (tid >= 288 && tid < 288 + LL) {
    int l = tid - 288;
    float s = 0.f;
    for (int n = 0; n < DS_; ++n) s += rb[n] * tl[n * LL + l];
    bias_l[(size_t)b * LL + l] = s;
  }
}

// ---------------- GN finalize (stats1 -> scale/shift) ----------------
__global__ __launch_bounds__(64) void k_gnfin(const float* __restrict__ stats,
                                              const float* __restrict__ gamma,
                                              const float* __restrict__ beta,
                                              float* __restrict__ scale,
                                              float* __restrict__ shift,
                                              int C, int cpg) {
  const int g = blockIdx.x, b = blockIdx.y;
  const int n = cpg << 4;
  float s = 0.f, q = 0.f;
  for (int i = threadIdx.x; i < n; i += 64) {
    int c = g * cpg + (i >> 4), pxb = i & 15;
    size_t idx = ((((size_t)b * C + c) << 4) + pxb) << 1;
    s += stats[idx];
    q += stats[idx + 1];
  }
#pragma unroll
  for (int off = 32; off > 0; off >>= 1) {
    s += __shfl_xor(s, off);
    q += __shfl_xor(q, off);
  }
  const float M = (float)(cpg << 10);
  float mean = s / M;
  float rsig = rsqrtf(q / M - mean * mean + 1e-5f);
  if ((int)threadIdx.x < cpg) {
    int c = g * cpg + threadIdx.x;
    float sc = rsig * gamma[c];
    scale[(size_t)b * C + c] = sc;
    shift[(size_t)b * C + c] = beta[c] - mean * sc;
  }
}

// ---------------- conv 3x3 via bf16 MFMA implicit GEMM (+GN stats, bf16 NHWC out) ----------------
template <int ICG, int GN>
__global__ __launch_bounds__(TPB) void k_conv_mfma(const ushort_t* __restrict__ in_h,
                                                   const ushort_t* __restrict__ wr,
                                                   const float* __restrict__ bias,
                                                   const float* __restrict__ iscale,
                                                   const float* __restrict__ ishift,
                                                   ushort_t* __restrict__ outp,
                                                   float* __restrict__ stats, int Cout) {
  const int ICPAD = ICG * 8;
  const int NS = ICG / 4;
  const int ICGS = 4 * 34 * 8 + 24;
  const int b   = blockIdx.z;
  const int ocb = blockIdx.y << 7;
  const int pxb = blockIdx.x;
  const int tid = threadIdx.x;
  const int w = tid >> 6, lane = tid & 63;
  const int lhi = lane >> 4, llo = lane & 15;

  __shared__ ushort_t in_t[ICG * ICGS];
  __shared__ float sc_l[GN ? ICG * 8 : 1], sh_l[GN ? ICG * 8 : 1];

  if (GN) {
    for (int i = tid; i < ICPAD; i += TPB) {
      sc_l[i] = iscale[(size_t)b * ICPAD + i];
      sh_l[i] = ishift[(size_t)b * ICPAD + i];
    }
    __syncthreads();
  }

  for (int u = tid; u < ICG * 8; u += TPB) {
    int icg = u >> 3, rem = u & 7, row = rem >> 1, col = (rem & 1) ? 33 : 0;
    *(s8v*)&in_t[icg * ICGS + (row * 34 + col) * 8] = (s8v){0, 0, 0, 0, 0, 0, 0, 0};
  }
  for (int r = 0; r < 4; ++r) {
    int gy = (pxb << 1) - 1 + r;
    if ((unsigned)gy < 32u) {
      const ushort_t* src = in_h + ((size_t)((b << 10) + (gy << 5))) * ICPAD;
      for (int u = tid; u < 32 * ICG; u += TPB) {
        int px = u / ICG, icg = u - px * ICG;
        s8v raw = *(const s8v*)(src + u * 8);
        if (GN) {
          s8v vv;
#pragma unroll
          for (int j = 0; j < 8; ++j) {
            int c = icg * 8 + j;
            float f = fmaxf(b2f((ushort_t)raw[j]) * sc_l[c] + sh_l[c], 0.f);
            vv[j] = (short)f2b(f);
          }
          raw = vv;
        }
        *(s8v*)&in_t[icg * ICGS + (r * 34 + px + 1) * 8] = raw;
      }
    } else {
      for (int u = tid; u < 32 * ICG; u += TPB) {
        int px = u / ICG, icg = u - px * ICG;
        *(s8v*)&in_t[icg * ICGS + (r * 34 + px + 1) * 8] = (s8v){0, 0, 0, 0, 0, 0, 0, 0};
      }
    }
  }
  __syncthreads();

  f4v acc[2][4];
#pragma unroll
  for (int i = 0; i < 2; ++i)
#pragma unroll
    for (int m = 0; m < 4; ++m) acc[i][m] = (f4v){0.f, 0.f, 0.f, 0.f};

  for (int t = 0; t < 9; ++t) {
    const int ky = t / 3, kx = t - ky * 3;
#pragma unroll
    for (int s = 0; s < NS; ++s) {
      const ushort_t* wp = wr + (((size_t)(t * NS + s) * Cout + ocb + w * 32 + llo) << 5) + lhi * 8;
      s8v a0 = *(const s8v*)(wp);
      s8v a1 = *(const s8v*)(wp + (16 << 5));
      const int icg = (s << 2) + lhi;
#pragma unroll
      for (int m = 0; m < 4; ++m) {
        const int row = (m >> 1) + ky;
        const int col = ((m & 1) << 4) + llo + kx;
        s8v bm = *(const s8v*)&in_t[icg * ICGS + (row * 34 + col) * 8];
        acc[0][m] = MFMA16(a0, bm, acc[0][m]);
        acc[1][m] = MFMA16(a1, bm, acc[1][m]);
      }
    }
  }

  __syncthreads();
  ushort_t* tb = in_t;  // [64 px][136]

#pragma unroll
  for (int i = 0; i < 2; ++i) {
#pragma unroll
    for (int r = 0; r < 4; ++r) {
      const int oc = ocb + w * 32 + i * 16 + lhi * 4 + r;
      const float bv = bias[oc];
      float sm = 0.f, sq = 0.f;
#pragma unroll
      for (int m = 0; m < 4; ++m) {
        float v = acc[i][m][r] + bv;
        tb[((m << 4) + llo) * 136 + (w * 32 + i * 16 + lhi * 4 + r)] = f2b(v);
        sm += v;
        sq += v * v;
      }
#pragma unroll
      for (int off = 1; off < 16; off <<= 1) {
        sm += __shfl_xor(sm, off);
        sq += __shfl_xor(sq, off);
      }
      if (llo == 0) {
        size_t sidx = ((((size_t)b * Cout + oc) << 4) + pxb) << 1;
        stats[sidx] = sm;
        stats[sidx + 1] = sq;
      }
    }
  }

  __syncthreads();
  for (int u = tid; u < 64 * 16; u += TPB) {
    int px = u >> 4, ch = u & 15;
    s8v val = *(const s8v*)&tb[px * 136 + ch * 8];
    *(s8v*)&outp[((size_t)((b << 10) + (pxb << 6) + px)) * Cout + ocb + ch * 8] = val;
  }
}

// x2raw NHWC bf16 + GN(folded gnfin)+relu + coords -> vso_h bf16 [b][1024][288]
__global__ __launch_bounds__(TPB) void k_build_vsoh(const ushort_t* __restrict__ x2raw,
                                                    const float* __restrict__ stats,
                                                    const float* __restrict__ gamma,
                                                    const float* __restrict__ beta,
                                                    ushort_t* __restrict__ dst) {
  const int pb = blockIdx.x;
  const int b  = blockIdx.y;
  const int tid = threadIdx.x;
  __shared__ float st_l[8192];
  __shared__ float sc_l[256], sh_l[256];
  for (int i = tid; i < 8192; i += TPB) st_l[i] = stats[(size_t)b * 8192 + i];
  __syncthreads();
  {
    int c = tid, g = c >> 3;
    float s = 0.f, q = 0.f;
    for (int j = 0; j < 8; ++j)
      for (int p = 0; p < 16; ++p) {
        int idx = (((g << 3) + j) * 16 + p) * 2;
        s += st_l[idx];
        q += st_l[idx + 1];
      }
    float mean = s / 8192.f;
    float rsig = rsqrtf(q / 8192.f - mean * mean + 1e-5f);
    float sc = rsig * gamma[c];
    sc_l[c] = sc;
    sh_l[c] = beta[c] - mean * sc;
  }
  __syncthreads();
  for (int u = tid; u < 64 * 36; u += TPB) {
    int px = u / 36, ch = u - px * 36;
    int p = (pb << 6) + px;
    s8v v;
    if (ch < 32) {
      s8v raw = *(const s8v*)(x2raw + ((size_t)((b << 10) + p)) * 256 + ch * 8);
#pragma unroll
      for (int j = 0; j < 8; ++j) {
        int c = ch * 8 + j;
        float f = fmaxf(b2f((ushort_t)raw[j]) * sc_l[c] + sh_l[c], 0.f);
        v[j] = (short)f2b(f);
      }
    } else {
#pragma unroll
      for (int j = 0; j < 8; ++j) {
        int cg = ch * 8 + j;
        float fv;
        if (cg == 256)      fv = -1.f + (2.f / 31.f) * (float)(p & 31);
        else if (cg == 257) fv = -1.f + (2.f / 31.f) * (float)(p >> 5);
        else                fv = 0.f;
        v[j] = (short)f2b(fv);
      }
    }
    *(s8v*)(dst + ((size_t)((b << 10) + p)) * 288 + ch * 8) = v;
  }
}

// ---------------- bf16 MFMA GEMM (LDS-bounced coalesced epilogues) ----------------
template <int MODE>
__global__ __launch_bounds__(TPB) void k_gemm_mfma(const ushort_t* __restrict__ A,
                                                   const ushort_t* __restrict__ Bw,
                                                   void* __restrict__ Cout,
                                                   const float* __restrict__ bias,
                                                   const float* __restrict__ mod) {
  const int wg = blockIdx.x;
  const int xcd = wg & 7;
  const int s2 = wg >> 3;
  const int b = xcd * 4 + (s2 / 24);
  const int rem = s2 - (s2 / 24) * 24;
  const int n0 = (rem % 3) << 7;
  const int m0 = (rem / 3) << 7;
  const int tid = threadIdx.x;
  const int w = tid >> 6, lane = tid & 63;
  const int wr = w >> 1, wc = w & 1;
  const int lhi = lane >> 4, llo = lane & 15;

  __shared__ ushort_t smem[2 * 128 * 40];
  ushort_t* A_l = smem;
  ushort_t* B_l = smem + 128 * 40;

  f4v acc[4][4];
#pragma unroll
  for (int i = 0; i < 4; ++i)
#pragma unroll
    for (int j = 0; j < 4; ++j) acc[i][j] = (f4v){0.f, 0.f, 0.f, 0.f};

  const ushort_t* Ab = A + (((size_t)b << 10)) * 288;

  for (int k0 = 0; k0 < 288; k0 += 32) {
    for (int u = tid; u < 512; u += TPB) {
      int row = u >> 2, seg = u & 3;
      *(s8v*)&A_l[row * 40 + seg * 8] = *(const s8v*)(Ab + (size_t)(m0 + row) * 288 + k0 + seg * 8);
      *(s8v*)&B_l[row * 40 + seg * 8] = *(const s8v*)(Bw + (size_t)(n0 + row) * 288 + k0 + seg * 8);
    }
    __syncthreads();
    s8v am[4], bn[4];
#pragma unroll
    for (int i = 0; i < 4; ++i) am[i] = *(const s8v*)&A_l[(wr * 64 + i * 16 + llo) * 40 + lhi * 8];
#pragma unroll
    for (int j = 0; j < 4; ++j) bn[j] = *(const s8v*)&B_l[(wc * 64 + j * 16 + llo) * 40 + lhi * 8];
#pragma unroll
    for (int i = 0; i < 4; ++i)
#pragma unroll
      for (int j = 0; j < 4; ++j) {
        if (MODE == 2) acc[i][j] = MFMA16(bn[j], am[i], acc[i][j]);
        else           acc[i][j] = MFMA16(am[i], bn[j], acc[i][j]);
      }
    __syncthreads();
  }

  ushort_t* T = smem;  // [64][136]

  if (MODE == 1) {
    ushort_t* Cb = (ushort_t*)Cout + (size_t)b * 1024 * 288;
    const int nch = (n0 == 256) ? 4 : 16;
#pragma unroll
    for (int h = 0; h < 2; ++h) {
      __syncthreads();
      if (wr == h) {
#pragma unroll
        for (int j = 0; j < 4; ++j) {
          int n = n0 + wc * 64 + j * 16 + llo;
          bool real = n < VF_;
          float bv = real ? bias[n] : 0.f;
          float sm = real ? mod[(size_t)b * VF_ + n] : 0.f;
          int coll = wc * 64 + j * 16 + llo;
#pragma unroll
          for (int i = 0; i < 4; ++i)
#pragma unroll
            for (int r = 0; r < 4; ++r) {
              int rowl = i * 16 + lhi * 4 + r;
              T[rowl * 136 + coll] = f2b(real ? (acc[i][j][r] + bv) * sm : 0.f);
            }
        }
      }
      __syncthreads();
      for (int u = tid; u < 64 * nch; u += TPB) {
        int rowl = u / nch, ch = u - rowl * nch;
        int m = m0 + h * 64 + rowl;
        *(s8v*)&Cb[(size_t)m * 288 + n0 + ch * 8] = *(const s8v*)&T[rowl * 136 + ch * 8];
      }
    }
  } else {
    ushort_t* Cb = (ushort_t*)Cout + (size_t)b * 32 * 272 * 32;
    const int mc0 = m0 >> 5;
#pragma unroll
    for (int h = 0; h < 2; ++h) {
      __syncthreads();
      if (wc == h) {
#pragma unroll
        for (int j = 0; j < 4; ++j)
#pragma unroll
          for (int r = 0; r < 4; ++r) {
            int n = n0 + h * 64 + j * 16 + lhi * 4 + r;
            int rowl = j * 16 + lhi * 4 + r;
            bool real = n < VF_;
            float bv = real ? bias[n] : 0.f;
#pragma unroll
            for (int i = 0; i < 4; ++i) {
              int coll = wr * 64 + i * 16 + llo;
              T[rowl * 136 + coll] = f2b(real ? acc[i][j][r] + bv : 0.f);
            }
          }
      }
      __syncthreads();
      for (int u = tid; u < 64 * 16; u += TPB) {
        int rowl = u >> 4, ch = u & 15;
        int n = n0 + h * 64 + rowl;
        if (n >= 272) continue;
        int mcblk = ch >> 2, within = ch & 3;
        *(s8v*)&Cb[(((size_t)(mc0 + mcblk) * 272 + n) << 5) + within * 8] =
            *(const s8v*)&T[rowl * 136 + ch * 8];
      }
    }
  }
}

// ---------------- txt cross-attention v3 (LDS-staged vsoh reads) ----------------
__global__ __launch_bounds__(TPB) void k_txtattn(const ushort_t* __restrict__ vsoh,
                                                 const float* __restrict__ wl,
                                                 const float* __restrict__ bias_l,
                                                 const float* __restrict__ txt,
                                                 float* __restrict__ out) {
  const int b = blockIdx.y;
  const int p0 = blockIdx.x << 8;
  const int tid = threadIdx.x;
  __shared__ float wls[288 * LL];
  __shared__ float tl[DS_ * LL];
  __shared__ float vs_l[256][33];
  for (int i = tid; i < 288 * LL; i += TPB) wls[i] = wl[(size_t)b * 288 * LL + i];
  for (int i = tid; i < DS_ * LL; i += TPB) tl[i] = txt[(size_t)b * DS_ * LL + i];

  float lg[LL];
  {
    const float* bl = bias_l + (size_t)b * LL;
#pragma unroll
    for (int l = 0; l < LL; ++l) lg[l] = bl[l];
  }

  for (int cc = 0; cc < 9; ++cc) {
    __syncthreads();
    for (int u = tid; u < 1024; u += TPB) {
      int px = u >> 2, seg = u & 3;
      s8v raw = *(const s8v*)(vsoh + ((size_t)((b << 10) + p0 + px)) * 288 + cc * 32 + seg * 8);
#pragma unroll
      for (int j = 0; j < 8; ++j) vs_l[px][seg * 8 + j] = b2f((ushort_t)raw[j]);
    }
    __syncthreads();
    const float* vrow = vs_l[tid];
#pragma unroll 4
    for (int j = 0; j < 32; ++j) {
      float f = vrow[j];
      const float* wr = &wls[(cc * 32 + j) * LL];
#pragma unroll
      for (int l = 0; l < LL; ++l) lg[l] += f * wr[l];
    }
  }

  const float sc = 0.057735026919f;  // 1/sqrt(300)
  float mx = lg[0] * sc;
#pragma unroll
  for (int l = 1; l < LL; ++l) mx = fmaxf(mx, lg[l] * sc);
  float sum = 0.f;
#pragma unroll
  for (int l = 0; l < LL; ++l) {
    lg[l] = __expf(lg[l] * sc - mx);
    sum += lg[l];
  }
  float inv = 1.f / sum;
#pragma unroll
  for (int l = 0; l < LL; ++l) lg[l] *= inv;
  float* ob = out + (((size_t)b * 558 + VF_) << 10) + p0 + tid;
  for (int d = 0; d < DS_; ++d) {
    const float* tr = tl + d * LL;
    float s = 0.f;
#pragma unroll
    for (int l = 0; l < LL; ++l) s += lg[l] * tr[l];
    ob[(size_t)d << 10] = s;
  }
}

// ---------------- video self-attention: bf16 MFMA flash v7 (dbuf LDS, 1 barrier/chunk) ----------------
__global__ __launch_bounds__(256, 2) void k_flash_mfma(const ushort_t* __restrict__ Kb,
                                                       const ushort_t* __restrict__ Qb,
                                                       const ushort_t* __restrict__ Vtb,
                                                       float* __restrict__ out) {
  const int wg = blockIdx.x;
  const int xcd = wg & 7, s = wg >> 3;
  const int b = xcd * 4 + (s >> 4);
  const int n0 = (s & 15) << 6;
  const int tid = threadIdx.x;
  const int w = tid >> 6, lane = tid & 63;
  const int lhi = lane >> 4;
  const int llo = lane & 15;

  __shared__ ushort_t q_l[2][9 * 1032];
  __shared__ ushort_t v_l[2][17 * 520];

  s8v kf[9];
  {
    const ushort_t* kp = Kb + ((size_t)(b * 1024 + n0 + w * 16 + llo)) * 288 + lhi * 8;
#pragma unroll
    for (int ks = 0; ks < 9; ++ks) kf[ks] = *(const s8v*)(kp + ks * 32);
  }

  const ushort_t* Qbase = Qb + (((size_t)b << 10)) * 288;
  const ushort_t* Vbase = Vtb + (size_t)b * 32 * 272 * 32;

  s8v qs[5], vs[5];
  auto ISSUE = [&](int mc) {
#pragma unroll
    for (int i = 0; i < 5; ++i) {
      int u = tid + (i << 8);
      if (u < 1152) {
        int ks = u >> 7, t = u & 127;
        int row = ((t >> 2) & 15) | ((t & 64) >> 2);
        int seg = t & 3;
        qs[i] = *(const s8v*)(Qbase + (size_t)((mc << 5) + row) * 288 + ks * 32 + seg * 8);
      }
      if (u < 1088) vs[i] = *(const s8v*)(Vbase + (size_t)mc * 8704 + (u << 3));
    }
  };
  auto WRITE = [&](int buf) {
#pragma unroll
    for (int i = 0; i < 5; ++i) {
      int u = tid + (i << 8);
      if (u < 1152) *(s8v*)&q_l[buf][(u >> 7) * 1032 + ((u & 127) << 3)] = qs[i];
      if (u < 1088) *(s8v*)&v_l[buf][(u << 3) + ((u >> 6) << 3)] = vs[i];
    }
  };

  f4v oacc[17];
#pragma unroll
  for (int i = 0; i < 17; ++i) oacc[i] = (f4v){0.f, 0.f, 0.f, 0.f};
  float mreg = -1e30f, lreg = 0.f;

  const float sc = 0.0622572819f;  // 1/sqrt(258)
  const int srcA = llo + ((lhi & 1) << 5);
  const int srcB = srcA + 16;
  const bool hi2 = lhi >= 2;
  const int qoff = (llo << 5) + (lhi << 3);

  ISSUE(0);
  WRITE(0);
  __syncthreads();
  ISSUE(1);

  for (int mc = 0; mc < 32; ++mc) {
    const int cur = mc & 1;
    const ushort_t* ql = q_l[cur];
    const ushort_t* vl = v_l[cur];

    f4v sacc0 = {0.f, 0.f, 0.f, 0.f}, sacc1 = {0.f, 0.f, 0.f, 0.f};
    __builtin_amdgcn_s_setprio(1);
#pragma unroll
    for (int ks = 0; ks < 9; ++ks) {
      s8v q0 = *(const s8v*)&ql[ks * 1032 + qoff];
      s8v q1 = *(const s8v*)&ql[ks * 1032 + 512 + qoff];
      sacc0 = MFMA16(q0, kf[ks], sacc0);
      sacc1 = MFMA16(q1, kf[ks], sacc1);
    }
    __builtin_amdgcn_s_setprio(0);

    float pmax = fmaxf(fmaxf(fmaxf(sacc0[0], sacc0[1]), fmaxf(sacc0[2], sacc0[3])),
                       fmaxf(fmaxf(sacc1[0], sacc1[1]), fmaxf(sacc1[2], sacc1[3])));
    pmax = fmaxf(pmax, __shfl_xor(pmax, 16));
    pmax = fmaxf(pmax, __shfl_xor(pmax, 32));
    float mn = fmaxf(mreg, pmax * sc);
    float alpha = __expf(mreg - mn);
    mreg = mn;

    float p0[4], p1[4];
    float rsum = 0.f;
#pragma unroll
    for (int r = 0; r < 4; ++r) {
      p0[r] = __expf(sacc0[r] * sc - mn);
      p1[r] = __expf(sacc1[r] * sc - mn);
      rsum += p0[r] + p1[r];
    }
    rsum += __shfl_xor(rsum, 16);
    rsum += __shfl_xor(rsum, 32);
    lreg = lreg * alpha + rsum;

    unsigned u0, u1, u2, u3;
    asm("v_cvt_pk_bf16_f32 %0, %1, %2" : "=v"(u0) : "v"(p0[0]), "v"(p0[1]));
    asm("v_cvt_pk_bf16_f32 %0, %1, %2" : "=v"(u1) : "v"(p0[2]), "v"(p0[3]));
    asm("v_cvt_pk_bf16_f32 %0, %1, %2" : "=v"(u2) : "v"(p1[0]), "v"(p1[1]));
    asm("v_cvt_pk_bf16_f32 %0, %1, %2" : "=v"(u3) : "v"(p1[2]), "v"(p1[3]));
    unsigned s0a = __shfl(u0, srcA, 64), s2a = __shfl(u2, srcA, 64);
    unsigned s1a = __shfl(u1, srcA, 64), s3a = __shfl(u3, srcA, 64);
    unsigned s0b = __shfl(u0, srcB, 64), s2b = __shfl(u2, srcB, 64);
    unsigned s1b = __shfl(u1, srcB, 64), s3b = __shfl(u3, srcB, 64);
    u4v pu;
    pu[0] = hi2 ? s2a : s0a;
    pu[1] = hi2 ? s3a : s1a;
    pu[2] = hi2 ? s2b : s0b;
    pu[3] = hi2 ? s3b : s1b;
    s8v pf = __builtin_bit_cast(s8v, pu);

    __builtin_amdgcn_s_setprio(1);
#pragma unroll
    for (int dt = 0; dt < 17; ++dt) {
      s8v vf = *(const s8v*)&vl[dt * 520 + qoff];
      f4v o = oacc[dt];
      o[0] *= alpha; o[1] *= alpha; o[2] *= alpha; o[3] *= alpha;
      oacc[dt] = MFMA16(vf, pf, o);
    }
    __builtin_amdgcn_s_setprio(0);

    if (mc < 31) {
      WRITE(cur ^ 1);
      if (mc < 30) ISSUE(mc + 2);
    }
    __syncthreads();
  }

  float linv = 1.f / lreg;
  const int n = n0 + w * 16 + llo;
#pragma unroll
  for (int dt = 0; dt < 17; ++dt) {
#pragma unroll
    for (int r = 0; r < 4; ++r) {
      int d = dt * 16 + lhi * 4 + r;
      if (d < VF_) out[((size_t)(b * 558 + d) << 10) + n] = oacc[dt][r] * linv;
    }
  }
}

// ---------------- launcher ----------------
extern "C" void kernel_launch(void* const* d_in, const int* in_sizes, int n_in,
                              void* d_out, int out_size, void* d_ws, size_t ws_size,
                              hipStream_t stream) {
  const float* spatial = (const float*)d_in[0];
  const float* video   = (const float*)d_in[1];
  const float* txt     = (const float*)d_in[2];
  const float* c1w = (const float*)d_in[3];
  const float* c1b = (const float*)d_in[4];
  const float* g1g = (const float*)d_in[5];
  const float* g1b = (const float*)d_in[6];
  const float* c2w = (const float*)d_in[7];
  const float* c2b = (const float*)d_in[8];
  const float* g2g = (const float*)d_in[9];
  const float* g2b = (const float*)d_in[10];
  const float* rw  = (const float*)d_in[11];
  const float* rb  = (const float*)d_in[12];
  const float* kw  = (const float*)d_in[13];
  const float* kb  = (const float*)d_in[14];
  const float* qw  = (const float*)d_in[15];
  const float* qb  = (const float*)d_in[16];
  const float* vw  = (const float*)d_in[17];
  const float* vb  = (const float*)d_in[18];
  const float* iw  = (const float*)d_in[19];
  const float* ib  = (const float*)d_in[20];
  float* out = (float*)d_out;
  float* ws = (float*)d_ws;

  // ws layout (float offsets), lifetime-aliased
  ushort_t* x0h    = (ushort_t*)(ws + 0);          // dead after conv1
  ushort_t* x1raw  = (ushort_t*)(ws + 5000000);    // dead after conv2
  ushort_t* kb16   = (ushort_t*)(ws + 10000000);
  ushort_t* x2raw  = (ushort_t*)(ws + 11500000);   // dead before kq GEMMs
  ushort_t* qb16   = (ushort_t*)(ws + 15800000);
  ushort_t* vsoh   = (ushort_t*)(ws + 20600000);
  ushort_t* vtb16  = (ushort_t*)(ws + 25400000);
  ushort_t* wcat   = (ushort_t*)(ws + 29900000);
  ushort_t* w1r    = (ushort_t*)(ws + 30140000);
  ushort_t* w2r    = (ushort_t*)(ws + 30310000);
  float*    mod    = ws + 30460000;
  float*    stats1 = ws + 30500000;
  float*    stats2 = ws + 30700000;
  float*    scale1 = ws + 31000000;
  float*    shift1 = ws + 31010000;
  float*    wl     = ws + 31050000;
  float*    bias_l = ws + 31240000;

  k_wl<<<dim3(32), 384, 0, stream>>>(rw, rb, txt, wl, bias_l);

  k_prep<<<dim3(4288), TPB, 0, stream>>>(c1w, c2w, kw, qw, vw, txt, iw, ib,
                                         video, spatial,
                                         w1r, w2r, wcat, mod, x0h);

  k_conv_mfma<36, 0><<<dim3(16, 1, NB), TPB, 0, stream>>>(x0h, w1r, c1b, nullptr, nullptr,
                                                          x1raw, stats1, C1);
  k_gnfin<<<dim3(32, NB), 64, 0, stream>>>(stats1, g1g, g1b, scale1, shift1, C1, 4);

  k_conv_mfma<16, 1><<<dim3(16, 2, NB), TPB, 0, stream>>>(x1raw, w2r, c2b, scale1, shift1,
                                                          x2raw, stats2, C2);
  k_build_vsoh<<<dim3(16, NB), TPB, 0, stream>>>(x2raw, stats2, g2g, g2b, vsoh);

  k_txtattn<<<dim3(4, NB), TPB, 0, stream>>>(vsoh, wl, bias_l, txt, out);

  k_gemm_mfma<1><<<dim3(768), TPB, 0, stream>>>(vsoh, wcat + 0 * 110592, (void*)kb16, kb, mod);
  k_gemm_mfma<1><<<dim3(768), TPB, 0, stream>>>(vsoh, wcat + 1 * 110592, (void*)qb16, qb, mod);
  k_gemm_mfma<2><<<dim3(768), TPB, 0, stream>>>(vsoh, wcat + 2 * 110592, (void*)vtb16, vb, nullptr);

  k_flash_mfma<<<dim3(512), 256, 0, stream>>>(kb16, qb16, vtb16, out);
}